// Round 14
// baseline (1707.504 us; speedup 1.0000x reference)
//
#include <hip/hip_runtime.h>
#include <cmath>

// RouterCond fused, round 14: LDS-port-volume attack. A (x) never staged in
// LDS — per-lane direct global loads + in-register fp16x2 split (r10-proven
// path on the r9 geometry). BK=64, B-only LDS dbuf 2x64KB via global_load_lds.
// One barrier per iter (288 total). No phase tricks (r11/r13 falsified them).
#define N_TOK 32768
#define D0    1024
#define DCC   512
#define DIN   1536
#define JD    3072
#define NE    64
#define BM    128
#define BJ    256
#define BK    64
#define NJC   (JD/BJ)      // 12
#define NIT   (DIN/BK)     // 24
#define NTH   512
#define HS    36
#define EPSV  1e-9f

typedef _Float16 half8 __attribute__((ext_vector_type(8)));
typedef float    f32x4 __attribute__((ext_vector_type(4)));

// ---- LDS: B double buffer only. Buf = [pl(2)][koct(8)][col(256)] granules = 64KB.
#define SZ_B  65536
#define LDS_TOTAL 131072           // bufs at 0, 65536
#define OFF_H    0                 // GEMM2 H slabs (8x9216=73728) alias bufs (fenced)
#define OFF_LRED 0                 // epilogue [128][68] f32 (H dead)
#define OFF_EPI  36864

#define W1T_G (192*3072)
#define W2T_G (384*64)

__device__ __forceinline__ f32x4 mfma16(half8 a, half8 b, f32x4 c) {
    return __builtin_amdgcn_mfma_f32_16x16x32_f16(a, b, c, 0, 0, 0);
}

__device__ __forceinline__ void split8(const float4 v0, const float4 v1, half8& hh, half8& hl) {
    float f[8] = {v0.x, v0.y, v0.z, v0.w, v1.x, v1.y, v1.z, v1.w};
    #pragma unroll
    for (int i = 0; i < 8; ++i) {
        _Float16 h = (_Float16)f[i];
        hh[i] = h;
        hl[i] = (_Float16)(f[i] - (float)h);
    }
}

__device__ __forceinline__ void gload16(const void* g, void* l) {
    __builtin_amdgcn_global_load_lds(
        (const __attribute__((address_space(1))) unsigned int*)g,
        (__attribute__((address_space(3))) unsigned int*)l, 16, 0, 0);
}

// -------- prologue kernels (r7-r9 proven) --------
__global__ void presplit_w1t(const float* __restrict__ W1,
                             _Float16* __restrict__ hi, _Float16* __restrict__ lo) {
    int g = blockIdx.x * blockDim.x + threadIdx.x;
    if (g >= W1T_G) return;
    const int j  = g % JD;
    const int ko = g / JD;
    const float* src = W1 + (size_t)j * DIN + ko * 8;
    float4 v0 = *(const float4*)src;
    float4 v1 = *(const float4*)(src + 4);
    half8 h, l;
    split8(v0, v1, h, l);
    *(half8*)(hi + (size_t)g * 8) = h;
    *(half8*)(lo + (size_t)g * 8) = l;
}

__global__ void presplit_w2t(const float* __restrict__ W2,
                             _Float16* __restrict__ hi, _Float16* __restrict__ lo) {
    int g = blockIdx.x * blockDim.x + threadIdx.x;
    if (g >= W2T_G) return;
    const int e  = g & 63;
    const int jo = g >> 6;
    const float* src = W2 + (size_t)e * JD + jo * 8;
    float4 v0 = *(const float4*)src;
    float4 v1 = *(const float4*)(src + 4);
    half8 h, l;
    split8(v0, v1, h, l);
    *(half8*)(hi + (size_t)g * 8) = h;
    *(half8*)(lo + (size_t)g * 8) = l;
}

// -------- main fused kernel --------
__global__ __launch_bounds__(NTH, 1)
void router_v14(const float* __restrict__ inp, const float* __restrict__ cnd,
                const _Float16* __restrict__ W1h, const _Float16* __restrict__ W1l,
                const _Float16* __restrict__ W2h, const _Float16* __restrict__ W2l,
                float* __restrict__ out_mask, float* __restrict__ out_topi,
                float* __restrict__ out_rp, float* __restrict__ out_probs)
{
    __shared__ __align__(16) char smem[LDS_TOTAL];

    const int tid  = threadIdx.x;
    const int lane = tid & 63;
    const int w    = tid >> 6;      // wave 0..7
    const int tg   = w >> 2;        // token half: rows tg*64..+63
    const int jg   = w & 3;         // j quarter (64 cols) / expert group (16)
    const int l15  = lane & 15;
    const int lg   = lane >> 4;     // k-oct within kstep, 0..3
    const int t0   = blockIdx.x * BM;

    // B staging roles: wave -> (plane, koct pair)
    const int bpl = w >> 2;                // 0..1
    const int kp  = (w & 3) * 2;           // kocts kp, kp+1 (of 8)

    // B frag byte offsets (plane0, ks0); ks adds 16384, lo plane adds 32768
    int boff[4];
    #pragma unroll
    for (int jf = 0; jf < 4; ++jf)
        boff[jf] = (lg * 256 + jg * 64 + jf * 16 + l15) * 16;

    // A per-lane fragment row pointers (4 row-tiles)
    const float* pI[4];
    const float* pC[4];
    #pragma unroll
    for (int tf = 0; tf < 4; ++tf) {
        const int row = t0 + tg * 64 + tf * 16 + l15;
        pI[tf] = inp + (size_t)row * D0;
        pC[tf] = cnd + (size_t)row * DCC;
    }

    const f32x4 vzero = {0.f, 0.f, 0.f, 0.f};
    f32x4 lacc[4] = {vzero, vzero, vzero, vzero};   // 64 tok x 16 experts

    const _Float16* const Wbp = bpl ? W1l : W1h;

    // wave-private GEMM2 H slab (aliases B bufs, barrier-fenced)
    _Float16* const myHh = (_Float16*)(smem + OFF_H + w * 9216);
    _Float16* const myHl = myHh + 2304;

    for (int jc = 0; jc < NJC; ++jc) {
        f32x4 acc1[4][4];
        #pragma unroll
        for (int tf = 0; tf < 4; ++tf)
            #pragma unroll
            for (int jf = 0; jf < 4; ++jf) acc1[tf][jf] = vzero;

        // ---- jc prologue: stage B(it=0) into buf0 (8 gload16/wave)
        {
            #pragma unroll
            for (int d = 0; d < 2; ++d) {
                const int koct = kp + d;
                const _Float16* src = Wbp + ((size_t)koct * JD + jc * BJ) * 8;
                char* dst = smem + ((bpl * 8 + koct) * 256) * 16;
                #pragma unroll
                for (int q = 0; q < 4; ++q)
                    gload16(src + (size_t)(q * 64 + lane) * 8, dst + q * 1024);
            }
        }
        __syncthreads();

        for (int it = 0; it < NIT; ++it) {
            const int cur = it & 1;
            const bool more = (it + 1 < NIT);

            // ---- issue x loads for both ksteps of this iter (per-lane rows)
            float4 xa[4][2], xb[4][2];
            const int k0 = it * BK + lg * 8;
            const int k1 = k0 + 32;
            #pragma unroll
            for (int tf = 0; tf < 4; ++tf) {
                const float* s0 = (k0 < D0) ? (pI[tf] + k0) : (pC[tf] + k0 - D0);
                xa[tf][0] = *(const float4*)s0;
                xa[tf][1] = *(const float4*)(s0 + 4);
            }
            #pragma unroll
            for (int tf = 0; tf < 4; ++tf) {
                const float* s1 = (k1 < D0) ? (pI[tf] + k1) : (pC[tf] + k1 - D0);
                xb[tf][0] = *(const float4*)s1;
                xb[tf][1] = *(const float4*)(s1 + 4);
            }
            __builtin_amdgcn_sched_barrier(0);   // x issued before B gloads

            // ---- issue B(it+1) gloads into other buffer (full-iter window)
            if (more) {
                char* bb = smem + (cur ^ 1) * SZ_B;
                #pragma unroll
                for (int d = 0; d < 2; ++d) {
                    const int koct = kp + d;
                    const _Float16* src = Wbp +
                        ((size_t)((it + 1) * 8 + koct) * JD + jc * BJ) * 8;
                    char* dst = bb + ((bpl * 8 + koct) * 256) * 16;
                    #pragma unroll
                    for (int q = 0; q < 4; ++q)
                        gload16(src + (size_t)(q * 64 + lane) * 8, dst + q * 1024);
                }
            }

            const char* bb = smem + cur * SZ_B;
            // ---- kstep 0: split xa in-register, B frags from LDS, 48 MFMAs
            {
                half8 ah[4], al[4], bh[4], bl[4];
                #pragma unroll
                for (int jf = 0; jf < 4; ++jf) {
                    bh[jf] = *(const half8*)(bb + boff[jf]);
                    bl[jf] = *(const half8*)(bb + boff[jf] + 32768);
                }
                #pragma unroll
                for (int tf = 0; tf < 4; ++tf) split8(xa[tf][0], xa[tf][1], ah[tf], al[tf]);
                #pragma unroll
                for (int tf = 0; tf < 4; ++tf)
                    #pragma unroll
                    for (int jf = 0; jf < 4; ++jf) {
                        acc1[tf][jf] = mfma16(ah[tf], bh[jf], acc1[tf][jf]);
                        acc1[tf][jf] = mfma16(ah[tf], bl[jf], acc1[tf][jf]);
                        acc1[tf][jf] = mfma16(al[tf], bh[jf], acc1[tf][jf]);
                    }
            }
            // ---- kstep 1 (xb wait covered by kstep-0 MFMAs)
            {
                half8 ah[4], al[4], bh[4], bl[4];
                #pragma unroll
                for (int jf = 0; jf < 4; ++jf) {
                    bh[jf] = *(const half8*)(bb + boff[jf] + 16384);
                    bl[jf] = *(const half8*)(bb + boff[jf] + 16384 + 32768);
                }
                #pragma unroll
                for (int tf = 0; tf < 4; ++tf) split8(xb[tf][0], xb[tf][1], ah[tf], al[tf]);
                #pragma unroll
                for (int tf = 0; tf < 4; ++tf)
                    #pragma unroll
                    for (int jf = 0; jf < 4; ++jf) {
                        acc1[tf][jf] = mfma16(ah[tf], bh[jf], acc1[tf][jf]);
                        acc1[tf][jf] = mfma16(ah[tf], bl[jf], acc1[tf][jf]);
                        acc1[tf][jf] = mfma16(al[tf], bh[jf], acc1[tf][jf]);
                    }
            }
            __syncthreads();   // drains B(it+1) gloads (issued ~4000 cy ago: cheap)
        }

        // ---- GELU + expert-split GEMM2 (r9-proven; H aliases B bufs, fenced)
        #pragma unroll
        for (int r = 0; r < 2; ++r) {
            #pragma unroll
            for (int c = 0; c < 2; ++c) {
                const int jf = 2*r + c;
                #pragma unroll
                for (int tf = 0; tf < 4; ++tf)
                    #pragma unroll
                    for (int rr = 0; rr < 4; ++rr) {
                        const float v = acc1[tf][jf][rr];
                        const float gv = 0.5f * v * (1.0f + erff(v * 0.70710678118654752f));
                        const _Float16 gh = (_Float16)gv;
                        const _Float16 gl = (_Float16)(gv - (float)gh);
                        const int o = (tf*16 + lg*4 + rr) * HS + c*16 + l15;
                        myHh[o] = gh; myHl[o] = gl;
                    }
            }
            __syncthreads();
            #pragma unroll
            for (int s = 0; s < 4; ++s) {
                const _Float16* sh = (const _Float16*)(smem + OFF_H + (tg*4 + s) * 9216);
                const _Float16* sl = sh + 2304;
                const int jo = jc*32 + s*8 + r*4 + lg;
                const size_t wg = ((size_t)jo * 64 + jg*16 + l15) * 8;
                half8 b2h = *(const half8*)(W2h + wg);
                half8 b2l = *(const half8*)(W2l + wg);
                #pragma unroll
                for (int tf = 0; tf < 4; ++tf) {
                    const int o = (tf*16 + l15) * HS + lg*8;
                    half8 a2h = *(const half8*)(sh + o);
                    half8 a2l = *(const half8*)(sl + o);
                    lacc[tf] = mfma16(a2h, b2h, lacc[tf]);
                    lacc[tf] = mfma16(a2h, b2l, lacc[tf]);
                    lacc[tf] = mfma16(a2l, b2h, lacc[tf]);
                }
            }
            __syncthreads();
        }
    }

    // ---- epilogue: wave owns 64tok x 16exp -> Lred, softmax + top-2, write
    float* const Lred = (float*)(smem + OFF_LRED);
    #pragma unroll
    for (int tf = 0; tf < 4; ++tf)
        #pragma unroll
        for (int rr = 0; rr < 4; ++rr)
            Lred[(tg*64 + tf*16 + lg*4 + rr) * 68 + jg*16 + l15] = lacc[tf][rr];
    __syncthreads();

    float* const mA   = (float*)(smem + OFF_EPI);
    float* const invA = mA + BM;
    int*   const i1A  = (int*)(invA + BM);
    int*   const i2A  = i1A + BM;
    float* const rp1A = (float*)(i2A + BM);
    float* const rp2A = rp1A + BM;

    if (tid < BM) {
        const float* row = Lred + tid * 68;
        float m = -3.402823466e38f;
        for (int e = 0; e < NE; ++e) m = fmaxf(m, row[e]);
        float s = 0.f, v1 = -3.402823466e38f, v2 = -3.402823466e38f;
        int i1 = 0, i2 = 0;
        for (int e = 0; e < NE; ++e) {
            const float v = row[e];
            s += expf(v - m);
            if (v > v1)      { v2 = v1; i2 = i1; v1 = v; i1 = e; }
            else if (v > v2) { v2 = v; i2 = e; }
        }
        const float inv = 1.f / s;
        const float p1 = fminf(expf(v1 - m) * inv + EPSV, 1.f - EPSV);
        const float p2 = fminf(expf(v2 - m) * inv + EPSV, 1.f - EPSV);
        mA[tid] = m; invA[tid] = inv; i1A[tid] = i1; i2A[tid] = i2;
        const float den = p1 + p2;
        rp1A[tid] = p1 / den; rp2A[tid] = p2 / den;
    }
    __syncthreads();

    for (int idx = tid; idx < BM * NE; idx += NTH) {
        const int r = idx >> 6, e = idx & 63;
        const size_t o = (size_t)(t0 + r) * NE + e;
        const float p = fminf(expf(Lred[r * 68 + e] - mA[r]) * invA[r] + EPSV, 1.f - EPSV);
        const int b1 = (e == i1A[r]), b2 = (e == i2A[r]);
        out_probs[o] = p;
        out_mask[o]  = (b1 | b2) ? 1.f : 0.f;
        out_rp[o]    = b1 ? rp1A[r] : (b2 ? rp2A[r] : 0.f);
    }
    if (tid < BM * 2) {
        const int r = tid >> 1, q = tid & 1;
        out_topi[(size_t)(t0 + r) * 2 + q] = (float)(q ? i2A[r] : i1A[r]);
    }
}

extern "C" void kernel_launch(void* const* d_in, const int* in_sizes, int n_in,
                              void* d_out, int out_size, void* d_ws, size_t ws_size,
                              hipStream_t stream) {
    const float* inp = (const float*)d_in[0];
    const float* cnd = (const float*)d_in[1];
    const float* W1  = (const float*)d_in[2];
    const float* W2  = (const float*)d_in[3];

    float* out = (float*)d_out;
    const size_t NT = (size_t)N_TOK;
    float* out_mask  = out;
    float* out_topi  = out + NT * NE;
    float* out_rp    = out + NT * NE + NT * 2;
    float* out_probs = out + NT * NE + NT * 2 + NT * NE;

    _Float16* W1h = (_Float16*)d_ws;
    _Float16* W1l = W1h + (size_t)W1T_G * 8;
    _Float16* W2h = W1l + (size_t)W1T_G * 8;
    _Float16* W2l = W2h + (size_t)W2T_G * 8;

    hipLaunchKernelGGL(presplit_w1t, dim3((W1T_G + 255) / 256), dim3(256), 0, stream, W1, W1h, W1l);
    hipLaunchKernelGGL(presplit_w2t, dim3((W2T_G + 255) / 256), dim3(256), 0, stream, W2, W2h, W2l);
    hipLaunchKernelGGL(router_v14, dim3(N_TOK / BM), dim3(NTH), 0, stream,
                       inp, cnd, W1h, W1l, W2h, W2l,
                       out_mask, out_topi, out_rp, out_probs);
}

// Round 15
// 1659.330 us; speedup vs baseline: 1.0290x; 1.0290x over previous
//
#include <hip/hip_runtime.h>
#include <cmath>

// RouterCond fused, round 15: barrier-free register-streaming GEMM1.
// x pre-split to fp16 hi/lo planes in ws (like W1/W2) -> A and B fragments are
// direct per-lane half8 global loads (L1/L2-resident), zero LDS / zero barriers
// in the k-loop, 2-unrolled rotating frag sets. GEMM2/epilogue = r9 verbatim.
// Fallback to the proven r9 kernel if ws_size too small.
#define N_TOK 32768
#define D0    1024
#define DCC   512
#define DIN   1536
#define JD    3072
#define NE    64
#define BM    128
#define BJ    256
#define NJC   (JD/BJ)      // 12
#define NIT   48           // k-steps of 32
#define NTH   512
#define HS    36
#define EPSV  1e-9f

typedef _Float16 half8 __attribute__((ext_vector_type(8)));
typedef float    f32x4 __attribute__((ext_vector_type(4)));

#define W1N   ((size_t)JD*DIN)        // 4718592 halves per plane
#define W2N   ((size_t)NE*JD)         // 196608 halves per plane
#define XTN   ((size_t)N_TOK*DIN)     // 50331648 halves per plane
#define XTG   (N_TOK*192)             // x granules per plane
#define W1T_G (192*3072)
#define W2T_G (384*64)

// ---- v15 LDS: H slabs only (8 x 9216 = 73728); Lred/epilogue alias.
#define V15_LDS   73728
#define V15_LRED  0
#define V15_EPI   36864

__device__ __forceinline__ f32x4 mfma16(half8 a, half8 b, f32x4 c) {
    return __builtin_amdgcn_mfma_f32_16x16x32_f16(a, b, c, 0, 0, 0);
}

__device__ __forceinline__ void split8(const float4 v0, const float4 v1, half8& hh, half8& hl) {
    float f[8] = {v0.x, v0.y, v0.z, v0.w, v1.x, v1.y, v1.z, v1.w};
    #pragma unroll
    for (int i = 0; i < 8; ++i) {
        _Float16 h = (_Float16)f[i];
        hh[i] = h;
        hl[i] = (_Float16)(f[i] - (float)h);
    }
}

__device__ __forceinline__ void gload16(const void* g, void* l) {
    __builtin_amdgcn_global_load_lds(
        (const __attribute__((address_space(1))) unsigned int*)g,
        (__attribute__((address_space(3))) unsigned int*)l, 16, 0, 0);
}

// -------- presplit kernels --------
__global__ void presplit_w1t(const float* __restrict__ W1,
                             _Float16* __restrict__ hi, _Float16* __restrict__ lo) {
    int g = blockIdx.x * blockDim.x + threadIdx.x;
    if (g >= W1T_G) return;
    const int j  = g % JD;
    const int ko = g / JD;
    const float* src = W1 + (size_t)j * DIN + ko * 8;
    float4 v0 = *(const float4*)src;
    float4 v1 = *(const float4*)(src + 4);
    half8 h, l;
    split8(v0, v1, h, l);
    *(half8*)(hi + (size_t)g * 8) = h;
    *(half8*)(lo + (size_t)g * 8) = l;
}

__global__ void presplit_w2t(const float* __restrict__ W2,
                             _Float16* __restrict__ hi, _Float16* __restrict__ lo) {
    int g = blockIdx.x * blockDim.x + threadIdx.x;
    if (g >= W2T_G) return;
    const int e  = g & 63;
    const int jo = g >> 6;
    const float* src = W2 + (size_t)e * JD + jo * 8;
    float4 v0 = *(const float4*)src;
    float4 v1 = *(const float4*)(src + 4);
    half8 h, l;
    split8(v0, v1, h, l);
    *(half8*)(hi + (size_t)g * 8) = h;
    *(half8*)(lo + (size_t)g * 8) = l;
}

// x -> row-major fp16 hi/lo planes (fully coalesced both sides)
__global__ void presplit_x(const float* __restrict__ inp, const float* __restrict__ cnd,
                           _Float16* __restrict__ hi, _Float16* __restrict__ lo) {
    int g = blockIdx.x * blockDim.x + threadIdx.x;
    if (g >= XTG) return;
    const int token = g / 192;
    const int ko    = g % 192;
    const float* src = (ko < 128) ? (inp + (size_t)token * D0 + ko * 8)
                                  : (cnd + (size_t)token * DCC + (ko - 128) * 8);
    float4 v0 = *(const float4*)src;
    float4 v1 = *(const float4*)(src + 4);
    half8 h, l;
    split8(v0, v1, h, l);
    *(half8*)(hi + (size_t)g * 8) = h;
    *(half8*)(lo + (size_t)g * 8) = l;
}

// ================= v15 main kernel =================
#define LOAD_FRAGS(AH, AL, BH, BL, IT) do {                                   \
    _Pragma("unroll")                                                         \
    for (int tf_ = 0; tf_ < 4; ++tf_) {                                       \
        const _Float16* p_ = baseX[tf_] + (size_t)(IT) * 32;                  \
        AH[tf_] = *(const half8*)p_;                                          \
        AL[tf_] = *(const half8*)(p_ + XTN);                                  \
    }                                                                         \
    _Pragma("unroll")                                                         \
    for (int jf_ = 0; jf_ < 4; ++jf_) {                                       \
        const _Float16* p_ = baseW[jf_] + (size_t)(IT) * 98304;               \
        BH[jf_] = *(const half8*)p_;                                          \
        BL[jf_] = *(const half8*)(p_ + W1N);                                  \
    }                                                                         \
} while (0)

#define DO_MFMA(AH, AL, BH, BL) do {                                          \
    _Pragma("unroll")                                                         \
    for (int tf_ = 0; tf_ < 4; ++tf_)                                         \
        _Pragma("unroll")                                                     \
        for (int jf_ = 0; jf_ < 4; ++jf_) {                                   \
            acc1[tf_][jf_] = mfma16(AH[tf_], BH[jf_], acc1[tf_][jf_]);        \
            acc1[tf_][jf_] = mfma16(AH[tf_], BL[jf_], acc1[tf_][jf_]);        \
            acc1[tf_][jf_] = mfma16(AL[tf_], BH[jf_], acc1[tf_][jf_]);        \
        }                                                                     \
} while (0)

__global__ __launch_bounds__(NTH, 1)
void router_v15(const _Float16* __restrict__ Xh,
                const _Float16* __restrict__ W1h,
                const _Float16* __restrict__ W2h, const _Float16* __restrict__ W2l,
                float* __restrict__ out_mask, float* __restrict__ out_topi,
                float* __restrict__ out_rp, float* __restrict__ out_probs)
{
    __shared__ __align__(16) char smem[V15_LDS];

    const int tid  = threadIdx.x;
    const int lane = tid & 63;
    const int w    = tid >> 6;      // wave 0..7
    const int tg   = w >> 2;        // token half: rows tg*64..+63
    const int jg   = w & 3;         // j quarter / expert group
    const int l15  = lane & 15;
    const int lg   = lane >> 4;     // k-oct 0..3
    const int t0   = blockIdx.x * BM;

    // per-lane fragment base pointers
    const _Float16* baseX[4];
    #pragma unroll
    for (int tf = 0; tf < 4; ++tf)
        baseX[tf] = Xh + (size_t)(t0 + tg*64 + tf*16 + l15) * DIN + lg*8;

    const f32x4 vzero = {0.f, 0.f, 0.f, 0.f};
    f32x4 lacc[4] = {vzero, vzero, vzero, vzero};   // 64 tok x 16 experts

    _Float16* const myHh = (_Float16*)(smem + w * 9216);
    _Float16* const myHl = myHh + 2304;

    for (int jc = 0; jc < NJC; ++jc) {
        f32x4 acc1[4][4];
        #pragma unroll
        for (int tf = 0; tf < 4; ++tf)
            #pragma unroll
            for (int jf = 0; jf < 4; ++jf) acc1[tf][jf] = vzero;

        const _Float16* baseW[4];
        #pragma unroll
        for (int jf = 0; jf < 4; ++jf)
            baseW[jf] = W1h + ((size_t)lg*3072 + jc*BJ + jg*64 + jf*16 + l15) * 8;

        // ---- barrier-free k-loop, 2-unrolled rotating frag sets
        half8 a0h[4], a0l[4], b0h[4], b0l[4];
        half8 a1h[4], a1l[4], b1h[4], b1l[4];
        LOAD_FRAGS(a0h, a0l, b0h, b0l, 0);
        for (int it = 0; it < NIT; it += 2) {
            if (it + 1 < NIT) LOAD_FRAGS(a1h, a1l, b1h, b1l, it + 1);
            DO_MFMA(a0h, a0l, b0h, b0l);
            if (it + 2 < NIT) LOAD_FRAGS(a0h, a0l, b0h, b0l, it + 2);
            if (it + 1 < NIT) DO_MFMA(a1h, a1l, b1h, b1l);
        }

        // ---- GELU + expert-split GEMM2 (r9-proven)
        #pragma unroll
        for (int r = 0; r < 2; ++r) {
            #pragma unroll
            for (int c = 0; c < 2; ++c) {
                const int jf = 2*r + c;
                #pragma unroll
                for (int tf = 0; tf < 4; ++tf)
                    #pragma unroll
                    for (int rr = 0; rr < 4; ++rr) {
                        const float v = acc1[tf][jf][rr];
                        const float gv = 0.5f * v * (1.0f + erff(v * 0.70710678118654752f));
                        const _Float16 gh = (_Float16)gv;
                        const _Float16 gl = (_Float16)(gv - (float)gh);
                        const int o = (tf*16 + lg*4 + rr) * HS + c*16 + l15;
                        myHh[o] = gh; myHl[o] = gl;
                    }
            }
            __syncthreads();
            #pragma unroll
            for (int s = 0; s < 4; ++s) {
                const _Float16* sh = (const _Float16*)(smem + (tg*4 + s) * 9216);
                const _Float16* sl = sh + 2304;
                const int jo = jc*32 + s*8 + r*4 + lg;
                const size_t wg = ((size_t)jo * 64 + jg*16 + l15) * 8;
                half8 b2h = *(const half8*)(W2h + wg);
                half8 b2l = *(const half8*)(W2l + wg);
                #pragma unroll
                for (int tf = 0; tf < 4; ++tf) {
                    const int o = (tf*16 + l15) * HS + lg*8;
                    half8 a2h = *(const half8*)(sh + o);
                    half8 a2l = *(const half8*)(sl + o);
                    lacc[tf] = mfma16(a2h, b2h, lacc[tf]);
                    lacc[tf] = mfma16(a2h, b2l, lacc[tf]);
                    lacc[tf] = mfma16(a2l, b2h, lacc[tf]);
                }
            }
            __syncthreads();
        }
    }

    // ---- epilogue (r9-proven)
    float* const Lred = (float*)(smem + V15_LRED);
    #pragma unroll
    for (int tf = 0; tf < 4; ++tf)
        #pragma unroll
        for (int rr = 0; rr < 4; ++rr)
            Lred[(tg*64 + tf*16 + lg*4 + rr) * 68 + jg*16 + l15] = lacc[tf][rr];
    __syncthreads();

    float* const mA   = (float*)(smem + V15_EPI);
    float* const invA = mA + BM;
    int*   const i1A  = (int*)(invA + BM);
    int*   const i2A  = i1A + BM;
    float* const rp1A = (float*)(i2A + BM);
    float* const rp2A = rp1A + BM;

    if (tid < BM) {
        const float* row = Lred + tid * 68;
        float m = -3.402823466e38f;
        for (int e = 0; e < NE; ++e) m = fmaxf(m, row[e]);
        float s = 0.f, v1 = -3.402823466e38f, v2 = -3.402823466e38f;
        int i1 = 0, i2 = 0;
        for (int e = 0; e < NE; ++e) {
            const float v = row[e];
            s += expf(v - m);
            if (v > v1)      { v2 = v1; i2 = i1; v1 = v; i1 = e; }
            else if (v > v2) { v2 = v; i2 = e; }
        }
        const float inv = 1.f / s;
        const float p1 = fminf(expf(v1 - m) * inv + EPSV, 1.f - EPSV);
        const float p2 = fminf(expf(v2 - m) * inv + EPSV, 1.f - EPSV);
        mA[tid] = m; invA[tid] = inv; i1A[tid] = i1; i2A[tid] = i2;
        const float den = p1 + p2;
        rp1A[tid] = p1 / den; rp2A[tid] = p2 / den;
    }
    __syncthreads();

    for (int idx = tid; idx < BM * NE; idx += NTH) {
        const int r = idx >> 6, e = idx & 63;
        const size_t o = (size_t)(t0 + r) * NE + e;
        const float p = fminf(expf(Lred[r * 68 + e] - mA[r]) * invA[r] + EPSV, 1.f - EPSV);
        const int b1 = (e == i1A[r]), b2 = (e == i2A[r]);
        out_probs[o] = p;
        out_mask[o]  = (b1 | b2) ? 1.f : 0.f;
        out_rp[o]    = b1 ? rp1A[r] : (b2 ? rp2A[r] : 0.f);
    }
    if (tid < BM * 2) {
        const int r = tid >> 1, q = tid & 1;
        out_topi[(size_t)(t0 + r) * 2 + q] = (float)(q ? i2A[r] : i1A[r]);
    }
}

// ================= r9 fallback kernel (proven, ws-small path) =================
#define V9_SZ_A  16384
#define V9_SZ_B  32768
#define V9_OFF_B 32768
#define V9_LDS   98304
#define V9_LRED  0
#define V9_EPI   36864

__global__ __launch_bounds__(NTH, 1)
void router_v9fb(const float* __restrict__ inp, const float* __restrict__ cnd,
                 const _Float16* __restrict__ W1h, const _Float16* __restrict__ W1l,
                 const _Float16* __restrict__ W2h, const _Float16* __restrict__ W2l,
                 float* __restrict__ out_mask, float* __restrict__ out_topi,
                 float* __restrict__ out_rp, float* __restrict__ out_probs)
{
    __shared__ __align__(16) char smem[V9_LDS];
    const int tid  = threadIdx.x;
    const int lane = tid & 63;
    const int w    = tid >> 6;
    const int tg   = w >> 2;
    const int jg   = w & 3;
    const int l15  = lane & 15;
    const int lg   = lane >> 4;
    const int t0   = blockIdx.x * BM;
    const int akoct = w >> 1;
    const int arow  = (w & 1) * 64 + lane;
    const int bplane = w >> 2;
    const int bkoct  = w & 3;

    int aoff[4], boff[4];
    #pragma unroll
    for (int tf = 0; tf < 4; ++tf) aoff[tf] = (lg*128 + tg*64 + tf*16 + l15) * 16;
    #pragma unroll
    for (int jf = 0; jf < 4; ++jf) boff[jf] = (lg*256 + jg*64 + jf*16 + l15) * 16;

    const f32x4 vzero = {0.f, 0.f, 0.f, 0.f};
    f32x4 lacc[4] = {vzero, vzero, vzero, vzero};
    const float* const xrowA = inp + (size_t)(t0 + arow) * D0;
    const float* const xrowC = cnd + (size_t)(t0 + arow) * DCC;
    const _Float16* const Wbp = bplane ? W1l : W1h;
    _Float16* const myHh = (_Float16*)(smem + w * 9216);
    _Float16* const myHl = myHh + 2304;

    for (int jc = 0; jc < NJC; ++jc) {
        f32x4 acc1[4][4];
        #pragma unroll
        for (int tf = 0; tf < 4; ++tf)
            #pragma unroll
            for (int jf = 0; jf < 4; ++jf) acc1[tf][jf] = vzero;
        {
            #pragma unroll
            for (int q = 0; q < 4; ++q) {
                const _Float16* src = Wbp + ((size_t)bkoct * JD + jc*BJ + q*64 + lane) * 8;
                char* dst = smem + V9_OFF_B + bplane*16384 + bkoct*4096 + q*1024;
                gload16(src, dst);
            }
            const float* sx = xrowA + akoct * 8;
            float4 v0 = *(const float4*)sx;
            float4 v1 = *(const float4*)(sx + 4);
            half8 hh, hl;
            split8(v0, v1, hh, hl);
            const int g = (akoct*128 + arow) * 16;
            *(half8*)(smem + g) = hh;
            *(half8*)(smem + 8192 + g) = hl;
        }
        __syncthreads();
        for (int it = 0; it < NIT; ++it) {
            const int cur = it & 1, nxt = cur ^ 1;
            const bool more = (it + 1 < NIT);
            float4 xv0, xv1;
            if (more) {
                const int ko = (it + 1) * 4 + bkoct;
                #pragma unroll
                for (int q = 0; q < 4; ++q) {
                    const _Float16* src = Wbp + ((size_t)ko * JD + jc*BJ + q*64 + lane) * 8;
                    char* dst = smem + V9_OFF_B + nxt*V9_SZ_B + bplane*16384 + bkoct*4096 + q*1024;
                    gload16(src, dst);
                }
                const int k = (it + 1) * 32 + akoct * 8;
                const float* sx = (k < D0) ? (xrowA + k) : (xrowC + k - D0);
                xv0 = *(const float4*)sx;
                xv1 = *(const float4*)(sx + 4);
            }
            const char* ab = smem + cur*V9_SZ_A;
            const char* bb = smem + V9_OFF_B + cur*V9_SZ_B;
            half8 ah[4], al[4], bh[4], bl[4];
            #pragma unroll
            for (int tf = 0; tf < 4; ++tf) {
                ah[tf] = *(const half8*)(ab + aoff[tf]);
                al[tf] = *(const half8*)(ab + 8192 + aoff[tf]);
            }
            #pragma unroll
            for (int jf = 0; jf < 4; ++jf) {
                bh[jf] = *(const half8*)(bb + boff[jf]);
                bl[jf] = *(const half8*)(bb + 16384 + boff[jf]);
            }
            #pragma unroll
            for (int tf = 0; tf < 4; ++tf)
                #pragma unroll
                for (int jf = 0; jf < 4; ++jf) {
                    acc1[tf][jf] = mfma16(ah[tf], bh[jf], acc1[tf][jf]);
                    acc1[tf][jf] = mfma16(ah[tf], bl[jf], acc1[tf][jf]);
                    acc1[tf][jf] = mfma16(al[tf], bh[jf], acc1[tf][jf]);
                }
            if (more) {
                half8 hh, hl;
                split8(xv0, xv1, hh, hl);
                const int g = (akoct*128 + arow) * 16;
                *(half8*)(smem + nxt*V9_SZ_A + g) = hh;
                *(half8*)(smem + nxt*V9_SZ_A + 8192 + g) = hl;
            }
            __syncthreads();
        }
        #pragma unroll
        for (int r = 0; r < 2; ++r) {
            #pragma unroll
            for (int c = 0; c < 2; ++c) {
                const int jf = 2*r + c;
                #pragma unroll
                for (int tf = 0; tf < 4; ++tf)
                    #pragma unroll
                    for (int rr = 0; rr < 4; ++rr) {
                        const float v = acc1[tf][jf][rr];
                        const float gv = 0.5f * v * (1.0f + erff(v * 0.70710678118654752f));
                        const _Float16 gh = (_Float16)gv;
                        const _Float16 gl = (_Float16)(gv - (float)gh);
                        const int o = (tf*16 + lg*4 + rr) * HS + c*16 + l15;
                        myHh[o] = gh; myHl[o] = gl;
                    }
            }
            __syncthreads();
            #pragma unroll
            for (int s = 0; s < 4; ++s) {
                const _Float16* sh = (const _Float16*)(smem + (tg*4 + s) * 9216);
                const _Float16* sl = sh + 2304;
                const int jo = jc*32 + s*8 + r*4 + lg;
                const size_t wg = ((size_t)jo * 64 + jg*16 + l15) * 8;
                half8 b2h = *(const half8*)(W2h + wg);
                half8 b2l = *(const half8*)(W2l + wg);
                #pragma unroll
                for (int tf = 0; tf < 4; ++tf) {
                    const int o = (tf*16 + l15) * HS + lg*8;
                    half8 a2h = *(const half8*)(sh + o);
                    half8 a2l = *(const half8*)(sl + o);
                    lacc[tf] = mfma16(a2h, b2h, lacc[tf]);
                    lacc[tf] = mfma16(a2h, b2l, lacc[tf]);
                    lacc[tf] = mfma16(a2l, b2h, lacc[tf]);
                }
            }
            __syncthreads();
        }
    }
    float* const Lred = (float*)(smem + V9_LRED);
    #pragma unroll
    for (int tf = 0; tf < 4; ++tf)
        #pragma unroll
        for (int rr = 0; rr < 4; ++rr)
            Lred[(tg*64 + tf*16 + lg*4 + rr) * 68 + jg*16 + l15] = lacc[tf][rr];
    __syncthreads();
    float* const mA   = (float*)(smem + V9_EPI);
    float* const invA = mA + BM;
    int*   const i1A  = (int*)(invA + BM);
    int*   const i2A  = i1A + BM;
    float* const rp1A = (float*)(i2A + BM);
    float* const rp2A = rp1A + BM;
    if (tid < BM) {
        const float* row = Lred + tid * 68;
        float m = -3.402823466e38f;
        for (int e = 0; e < NE; ++e) m = fmaxf(m, row[e]);
        float s = 0.f, v1 = -3.402823466e38f, v2 = -3.402823466e38f;
        int i1 = 0, i2 = 0;
        for (int e = 0; e < NE; ++e) {
            const float v = row[e];
            s += expf(v - m);
            if (v > v1)      { v2 = v1; i2 = i1; v1 = v; i1 = e; }
            else if (v > v2) { v2 = v; i2 = e; }
        }
        const float inv = 1.f / s;
        const float p1 = fminf(expf(v1 - m) * inv + EPSV, 1.f - EPSV);
        const float p2 = fminf(expf(v2 - m) * inv + EPSV, 1.f - EPSV);
        mA[tid] = m; invA[tid] = inv; i1A[tid] = i1; i2A[tid] = i2;
        const float den = p1 + p2;
        rp1A[tid] = p1 / den; rp2A[tid] = p2 / den;
    }
    __syncthreads();
    for (int idx = tid; idx < BM * NE; idx += NTH) {
        const int r = idx >> 6, e = idx & 63;
        const size_t o = (size_t)(t0 + r) * NE + e;
        const float p = fminf(expf(Lred[r * 68 + e] - mA[r]) * invA[r] + EPSV, 1.f - EPSV);
        const int b1 = (e == i1A[r]), b2 = (e == i2A[r]);
        out_probs[o] = p;
        out_mask[o]  = (b1 | b2) ? 1.f : 0.f;
        out_rp[o]    = b1 ? rp1A[r] : (b2 ? rp2A[r] : 0.f);
    }
    if (tid < BM * 2) {
        const int r = tid >> 1, q = tid & 1;
        out_topi[(size_t)(t0 + r) * 2 + q] = (float)(q ? i2A[r] : i1A[r]);
    }
}

extern "C" void kernel_launch(void* const* d_in, const int* in_sizes, int n_in,
                              void* d_out, int out_size, void* d_ws, size_t ws_size,
                              hipStream_t stream) {
    const float* inp = (const float*)d_in[0];
    const float* cnd = (const float*)d_in[1];
    const float* W1  = (const float*)d_in[2];
    const float* W2  = (const float*)d_in[3];

    float* out = (float*)d_out;
    const size_t NT = (size_t)N_TOK;
    float* out_mask  = out;
    float* out_topi  = out + NT * NE;
    float* out_rp    = out + NT * NE + NT * 2;
    float* out_probs = out + NT * NE + NT * 2 + NT * NE;

    const size_t V15_REQ = (2*XTN + 2*W1N + 2*W2N) * 2;   // ~221 MB
    if (ws_size >= V15_REQ) {
        _Float16* Xh  = (_Float16*)d_ws;
        _Float16* Xl  = Xh + XTN;
        _Float16* W1h = Xl + XTN;
        _Float16* W1l = W1h + W1N;
        _Float16* W2h = W1l + W1N;
        _Float16* W2l = W2h + W2N;
        hipLaunchKernelGGL(presplit_x,   dim3(XTG/256), dim3(256), 0, stream, inp, cnd, Xh, Xl);
        hipLaunchKernelGGL(presplit_w1t, dim3((W1T_G + 255)/256), dim3(256), 0, stream, W1, W1h, W1l);
        hipLaunchKernelGGL(presplit_w2t, dim3((W2T_G + 255)/256), dim3(256), 0, stream, W2, W2h, W2l);
        hipLaunchKernelGGL(router_v15, dim3(N_TOK / BM), dim3(NTH), 0, stream,
                           Xh, W1h, W2h, W2l, out_mask, out_topi, out_rp, out_probs);
    } else {
        _Float16* W1h = (_Float16*)d_ws;
        _Float16* W1l = W1h + W1N;
        _Float16* W2h = W1l + W1N;
        _Float16* W2l = W2h + W2N;
        hipLaunchKernelGGL(presplit_w1t, dim3((W1T_G + 255)/256), dim3(256), 0, stream, W1, W1h, W1l);
        hipLaunchKernelGGL(presplit_w2t, dim3((W2T_G + 255)/256), dim3(256), 0, stream, W2, W2h, W2l);
        hipLaunchKernelGGL(router_v9fb, dim3(N_TOK / BM), dim3(NTH), 0, stream,
                           inp, cnd, W1h, W1l, W2h, W2l,
                           out_mask, out_topi, out_rp, out_probs);
    }
}

// Round 16
// 1146.991 us; speedup vs baseline: 1.4887x; 1.4467x over previous
//
#include <hip/hip_runtime.h>
#include <cmath>

// RouterCond fused, round 16: r9 + zero-VALU staging. x pre-split to fp16
// hi/lo planes in ws, stored koct-major per-128-token tile so A staging is
// 2 contiguous global_load_lds per wave (like B). k-loop: 6 gload16/wave +
// 16 frag ds_reads + 48 MFMAs, one barrier. GEMM2/epilogue = r9 verbatim.
#define N_TOK 32768
#define D0    1024
#define DCC   512
#define DIN   1536
#define JD    3072
#define NE    64
#define BM    128
#define BJ    256
#define NJC   (JD/BJ)      // 12
#define NIT   48           // k-steps of 32
#define NTH   512
#define HS    36
#define EPSV  1e-9f

typedef _Float16 half8 __attribute__((ext_vector_type(8)));
typedef float    f32x4 __attribute__((ext_vector_type(4)));

// ---- LDS: A dbuf 2x16KB (granule [pl2][koct4][row128]), B dbuf 2x32KB
//      (granule [pl2][koct4][col256]). H/Lred/epilogue alias dead bufs.
#define SZ_A  16384
#define SZ_B  32768
#define OFF_A 0                    // A bufs: 0, 16384
#define OFF_B 32768                // B bufs: 32768, 65536
#define LDS_TOTAL 98304
#define OFF_H    0                 // 8 x 9216 = 73728, aliases A+B0 (fenced)
#define OFF_LRED 0
#define OFF_EPI  36864

#define W1N   ((size_t)JD*DIN)
#define W2N   ((size_t)NE*JD)
#define XTN   ((size_t)N_TOK*DIN)     // halves per x plane
#define XT_G  (256*192*128)           // x granules per plane (tile-major)
#define W1T_G (192*3072)
#define W2T_G (384*64)

__device__ __forceinline__ f32x4 mfma16(half8 a, half8 b, f32x4 c) {
    return __builtin_amdgcn_mfma_f32_16x16x32_f16(a, b, c, 0, 0, 0);
}

__device__ __forceinline__ void split8(const float4 v0, const float4 v1, half8& hh, half8& hl) {
    float f[8] = {v0.x, v0.y, v0.z, v0.w, v1.x, v1.y, v1.z, v1.w};
    #pragma unroll
    for (int i = 0; i < 8; ++i) {
        _Float16 h = (_Float16)f[i];
        hh[i] = h;
        hl[i] = (_Float16)(f[i] - (float)h);
    }
}

__device__ __forceinline__ void gload16(const void* g, void* l) {
    __builtin_amdgcn_global_load_lds(
        (const __attribute__((address_space(1))) unsigned int*)g,
        (__attribute__((address_space(3))) unsigned int*)l, 16, 0, 0);
}

// -------- presplit kernels --------
__global__ void presplit_w1t(const float* __restrict__ W1,
                             _Float16* __restrict__ hi, _Float16* __restrict__ lo) {
    int g = blockIdx.x * blockDim.x + threadIdx.x;
    if (g >= W1T_G) return;
    const int j  = g % JD;
    const int ko = g / JD;
    const float* src = W1 + (size_t)j * DIN + ko * 8;
    float4 v0 = *(const float4*)src;
    float4 v1 = *(const float4*)(src + 4);
    half8 h, l;
    split8(v0, v1, h, l);
    *(half8*)(hi + (size_t)g * 8) = h;
    *(half8*)(lo + (size_t)g * 8) = l;
}

__global__ void presplit_w2t(const float* __restrict__ W2,
                             _Float16* __restrict__ hi, _Float16* __restrict__ lo) {
    int g = blockIdx.x * blockDim.x + threadIdx.x;
    if (g >= W2T_G) return;
    const int e  = g & 63;
    const int jo = g >> 6;
    const float* src = W2 + (size_t)e * JD + jo * 8;
    float4 v0 = *(const float4*)src;
    float4 v1 = *(const float4*)(src + 4);
    half8 h, l;
    split8(v0, v1, h, l);
    *(half8*)(hi + (size_t)g * 8) = h;
    *(half8*)(lo + (size_t)g * 8) = l;
}

// x -> koct-major per-128-token-tile granules: Xt[tile][ko][row]
__global__ void presplit_xt(const float* __restrict__ inp, const float* __restrict__ cnd,
                            _Float16* __restrict__ hi, _Float16* __restrict__ lo) {
    int g = blockIdx.x * blockDim.x + threadIdx.x;
    if (g >= XT_G) return;
    const int r    = g & 127;
    const int ko   = (g >> 7) % 192;
    const int tile = g / (192 * 128);
    const int token = tile * 128 + r;
    const float* src = (ko < 128) ? (inp + (size_t)token * D0 + ko * 8)
                                  : (cnd + (size_t)token * DCC + (ko - 128) * 8);
    float4 v0 = *(const float4*)src;
    float4 v1 = *(const float4*)(src + 4);
    half8 h, l;
    split8(v0, v1, h, l);
    *(half8*)(hi + (size_t)g * 8) = h;   // writes fully coalesced
    *(half8*)(lo + (size_t)g * 8) = l;
}

// ================= v16 main kernel =================
__global__ __launch_bounds__(NTH, 1)
void router_v16(const _Float16* __restrict__ Xh, const _Float16* __restrict__ Xl,
                const _Float16* __restrict__ W1h, const _Float16* __restrict__ W1l,
                const _Float16* __restrict__ W2h, const _Float16* __restrict__ W2l,
                float* __restrict__ out_mask, float* __restrict__ out_topi,
                float* __restrict__ out_rp, float* __restrict__ out_probs)
{
    __shared__ __align__(16) char smem[LDS_TOTAL];

    const int tid  = threadIdx.x;
    const int lane = tid & 63;
    const int w    = tid >> 6;      // wave 0..7
    const int tg   = w >> 2;        // token half: rows tg*64..+63
    const int jg   = w & 3;         // j quarter / expert group
    const int l15  = lane & 15;
    const int lg   = lane >> 4;     // k-oct 0..3
    const int blk  = blockIdx.x;
    const int t0   = blk * BM;

    // staging roles (same for A and B): plane = w>>2, koct = w&3
    const int spl = w >> 2;
    const int sko = w & 3;

    int aoff[4], boff[4];
    #pragma unroll
    for (int tf = 0; tf < 4; ++tf) aoff[tf] = (lg*128 + tg*64 + tf*16 + l15) * 16;
    #pragma unroll
    for (int jf = 0; jf < 4; ++jf) boff[jf] = (lg*256 + jg*64 + jf*16 + l15) * 16;

    const f32x4 vzero = {0.f, 0.f, 0.f, 0.f};
    f32x4 lacc[4] = {vzero, vzero, vzero, vzero};   // 64 tok x 16 experts

    const _Float16* const Wbp = spl ? W1l : W1h;
    const _Float16* const Xbp = spl ? Xl  : Xh;
    // x tile base (granules): blk*192*128; staging src for iter it, koct sko:
    //   Xbp + ((blk*192 + it*4 + sko)*128 + q*64 + lane)*8   (contiguous/wave)
    const size_t xbase = (size_t)blk * 192 * 128;

    _Float16* const myHh = (_Float16*)(smem + OFF_H + w * 9216);
    _Float16* const myHl = myHh + 2304;

    for (int jc = 0; jc < NJC; ++jc) {
        f32x4 acc1[4][4];
        #pragma unroll
        for (int tf = 0; tf < 4; ++tf)
            #pragma unroll
            for (int jf = 0; jf < 4; ++jf) acc1[tf][jf] = vzero;

        // ---- prologue: stage it=0 into buf0 (A: 2 gload16, B: 4 gload16)
        {
            const _Float16* asrc = Xbp + (xbase + (size_t)(0 + sko) * 128) * 8;
            char* adst = smem + OFF_A + spl * 8192 + sko * 2048;
            gload16(asrc + (size_t)lane * 8, adst);
            gload16(asrc + (size_t)(64 + lane) * 8, adst + 1024);
            const _Float16* bsrc = Wbp + ((size_t)sko * JD + jc * BJ) * 8;
            char* bdst = smem + OFF_B + spl * 16384 + sko * 4096;
            #pragma unroll
            for (int q = 0; q < 4; ++q)
                gload16(bsrc + (size_t)(q * 64 + lane) * 8, bdst + q * 1024);
        }
        __syncthreads();

        for (int it = 0; it < NIT; ++it) {
            const int cur = it & 1, nxt = cur ^ 1;
            const bool more = (it + 1 < NIT);
            if (more) {   // stage it+1 into nxt buffers (zero VALU path)
                const _Float16* asrc = Xbp + (xbase + (size_t)((it + 1) * 4 + sko) * 128) * 8;
                char* adst = smem + OFF_A + nxt * SZ_A + spl * 8192 + sko * 2048;
                gload16(asrc + (size_t)lane * 8, adst);
                gload16(asrc + (size_t)(64 + lane) * 8, adst + 1024);
                const _Float16* bsrc = Wbp +
                    ((size_t)((it + 1) * 4 + sko) * JD + jc * BJ) * 8;
                char* bdst = smem + OFF_B + nxt * SZ_B + spl * 16384 + sko * 4096;
                #pragma unroll
                for (int q = 0; q < 4; ++q)
                    gload16(bsrc + (size_t)(q * 64 + lane) * 8, bdst + q * 1024);
            }
            // fragment reads from current buffers (contiguous, conflict-free)
            const char* ab = smem + OFF_A + cur * SZ_A;
            const char* bb = smem + OFF_B + cur * SZ_B;
            half8 ah[4], al[4], bh[4], bl[4];
            #pragma unroll
            for (int tf = 0; tf < 4; ++tf) {
                ah[tf] = *(const half8*)(ab + aoff[tf]);
                al[tf] = *(const half8*)(ab + 8192 + aoff[tf]);
            }
            #pragma unroll
            for (int jf = 0; jf < 4; ++jf) {
                bh[jf] = *(const half8*)(bb + boff[jf]);
                bl[jf] = *(const half8*)(bb + 16384 + boff[jf]);
            }
            #pragma unroll
            for (int tf = 0; tf < 4; ++tf)
                #pragma unroll
                for (int jf = 0; jf < 4; ++jf) {
                    acc1[tf][jf] = mfma16(ah[tf], bh[jf], acc1[tf][jf]);
                    acc1[tf][jf] = mfma16(ah[tf], bl[jf], acc1[tf][jf]);
                    acc1[tf][jf] = mfma16(al[tf], bh[jf], acc1[tf][jf]);
                }
            __syncthreads();   // drains it+1 gloads (issued a full iter ago)
        }

        // ---- GELU + expert-split GEMM2 (r9-proven; H aliases dead bufs)
        #pragma unroll
        for (int r = 0; r < 2; ++r) {
            #pragma unroll
            for (int c = 0; c < 2; ++c) {
                const int jf = 2*r + c;
                #pragma unroll
                for (int tf = 0; tf < 4; ++tf)
                    #pragma unroll
                    for (int rr = 0; rr < 4; ++rr) {
                        const float v = acc1[tf][jf][rr];
                        const float gv = 0.5f * v * (1.0f + erff(v * 0.70710678118654752f));
                        const _Float16 gh = (_Float16)gv;
                        const _Float16 gl = (_Float16)(gv - (float)gh);
                        const int o = (tf*16 + lg*4 + rr) * HS + c*16 + l15;
                        myHh[o] = gh; myHl[o] = gl;
                    }
            }
            __syncthreads();
            #pragma unroll
            for (int s = 0; s < 4; ++s) {
                const _Float16* sh = (const _Float16*)(smem + OFF_H + (tg*4 + s) * 9216);
                const _Float16* sl = sh + 2304;
                const int jo = jc*32 + s*8 + r*4 + lg;
                const size_t wg = ((size_t)jo * 64 + jg*16 + l15) * 8;
                half8 b2h = *(const half8*)(W2h + wg);
                half8 b2l = *(const half8*)(W2l + wg);
                #pragma unroll
                for (int tf = 0; tf < 4; ++tf) {
                    const int o = (tf*16 + l15) * HS + lg*8;
                    half8 a2h = *(const half8*)(sh + o);
                    half8 a2l = *(const half8*)(sl + o);
                    lacc[tf] = mfma16(a2h, b2h, lacc[tf]);
                    lacc[tf] = mfma16(a2h, b2l, lacc[tf]);
                    lacc[tf] = mfma16(a2l, b2h, lacc[tf]);
                }
            }
            __syncthreads();
        }
    }

    // ---- epilogue (r9-proven)
    float* const Lred = (float*)(smem + OFF_LRED);
    #pragma unroll
    for (int tf = 0; tf < 4; ++tf)
        #pragma unroll
        for (int rr = 0; rr < 4; ++rr)
            Lred[(tg*64 + tf*16 + lg*4 + rr) * 68 + jg*16 + l15] = lacc[tf][rr];
    __syncthreads();

    float* const mA   = (float*)(smem + OFF_EPI);
    float* const invA = mA + BM;
    int*   const i1A  = (int*)(invA + BM);
    int*   const i2A  = i1A + BM;
    float* const rp1A = (float*)(i2A + BM);
    float* const rp2A = rp1A + BM;

    if (tid < BM) {
        const float* row = Lred + tid * 68;
        float m = -3.402823466e38f;
        for (int e = 0; e < NE; ++e) m = fmaxf(m, row[e]);
        float s = 0.f, v1 = -3.402823466e38f, v2 = -3.402823466e38f;
        int i1 = 0, i2 = 0;
        for (int e = 0; e < NE; ++e) {
            const float v = row[e];
            s += expf(v - m);
            if (v > v1)      { v2 = v1; i2 = i1; v1 = v; i1 = e; }
            else if (v > v2) { v2 = v; i2 = e; }
        }
        const float inv = 1.f / s;
        const float p1 = fminf(expf(v1 - m) * inv + EPSV, 1.f - EPSV);
        const float p2 = fminf(expf(v2 - m) * inv + EPSV, 1.f - EPSV);
        mA[tid] = m; invA[tid] = inv; i1A[tid] = i1; i2A[tid] = i2;
        const float den = p1 + p2;
        rp1A[tid] = p1 / den; rp2A[tid] = p2 / den;
    }
    __syncthreads();

    for (int idx = tid; idx < BM * NE; idx += NTH) {
        const int r = idx >> 6, e = idx & 63;
        const size_t o = (size_t)(t0 + r) * NE + e;
        const float p = fminf(expf(Lred[r * 68 + e] - mA[r]) * invA[r] + EPSV, 1.f - EPSV);
        const int b1 = (e == i1A[r]), b2 = (e == i2A[r]);
        out_probs[o] = p;
        out_mask[o]  = (b1 | b2) ? 1.f : 0.f;
        out_rp[o]    = b1 ? rp1A[r] : (b2 ? rp2A[r] : 0.f);
    }
    if (tid < BM * 2) {
        const int r = tid >> 1, q = tid & 1;
        out_topi[(size_t)(t0 + r) * 2 + q] = (float)(q ? i2A[r] : i1A[r]);
    }
}

// ================= r9 fallback (ws-small path, proven) =================
__global__ __launch_bounds__(NTH, 1)
void router_v9fb(const float* __restrict__ inp, const float* __restrict__ cnd,
                 const _Float16* __restrict__ W1h, const _Float16* __restrict__ W1l,
                 const _Float16* __restrict__ W2h, const _Float16* __restrict__ W2l,
                 float* __restrict__ out_mask, float* __restrict__ out_topi,
                 float* __restrict__ out_rp, float* __restrict__ out_probs)
{
    __shared__ __align__(16) char smem[LDS_TOTAL];
    const int tid  = threadIdx.x;
    const int lane = tid & 63;
    const int w    = tid >> 6;
    const int tg   = w >> 2;
    const int jg   = w & 3;
    const int l15  = lane & 15;
    const int lg   = lane >> 4;
    const int t0   = blockIdx.x * BM;
    const int akoct = w >> 1;
    const int arow  = (w & 1) * 64 + lane;
    const int bplane = w >> 2;
    const int bkoct  = w & 3;

    int aoff[4], boff[4];
    #pragma unroll
    for (int tf = 0; tf < 4; ++tf) aoff[tf] = (lg*128 + tg*64 + tf*16 + l15) * 16;
    #pragma unroll
    for (int jf = 0; jf < 4; ++jf) boff[jf] = (lg*256 + jg*64 + jf*16 + l15) * 16;

    const f32x4 vzero = {0.f, 0.f, 0.f, 0.f};
    f32x4 lacc[4] = {vzero, vzero, vzero, vzero};
    const float* const xrowA = inp + (size_t)(t0 + arow) * D0;
    const float* const xrowC = cnd + (size_t)(t0 + arow) * DCC;
    const _Float16* const Wbp = bplane ? W1l : W1h;
    _Float16* const myHh = (_Float16*)(smem + w * 9216);
    _Float16* const myHl = myHh + 2304;

    for (int jc = 0; jc < NJC; ++jc) {
        f32x4 acc1[4][4];
        #pragma unroll
        for (int tf = 0; tf < 4; ++tf)
            #pragma unroll
            for (int jf = 0; jf < 4; ++jf) acc1[tf][jf] = vzero;
        {
            #pragma unroll
            for (int q = 0; q < 4; ++q) {
                const _Float16* src = Wbp + ((size_t)bkoct * JD + jc*BJ + q*64 + lane) * 8;
                gload16(src, smem + OFF_B + bplane*16384 + bkoct*4096 + q*1024);
            }
            const float* sx = xrowA + akoct * 8;
            float4 v0 = *(const float4*)sx;
            float4 v1 = *(const float4*)(sx + 4);
            half8 hh, hl;
            split8(v0, v1, hh, hl);
            const int g = (akoct*128 + arow) * 16;
            *(half8*)(smem + g) = hh;
            *(half8*)(smem + 8192 + g) = hl;
        }
        __syncthreads();
        for (int it = 0; it < NIT; ++it) {
            const int cur = it & 1, nxt = cur ^ 1;
            const bool more = (it + 1 < NIT);
            float4 xv0, xv1;
            if (more) {
                const int ko = (it + 1) * 4 + bkoct;
                #pragma unroll
                for (int q = 0; q < 4; ++q) {
                    const _Float16* src = Wbp + ((size_t)ko * JD + jc*BJ + q*64 + lane) * 8;
                    gload16(src, smem + OFF_B + nxt*SZ_B + bplane*16384 + bkoct*4096 + q*1024);
                }
                const int k = (it + 1) * 32 + akoct * 8;
                const float* sx = (k < D0) ? (xrowA + k) : (xrowC + k - D0);
                xv0 = *(const float4*)sx;
                xv1 = *(const float4*)(sx + 4);
            }
            const char* ab = smem + cur*SZ_A;
            const char* bb = smem + OFF_B + cur*SZ_B;
            half8 ah[4], al[4], bh[4], bl[4];
            #pragma unroll
            for (int tf = 0; tf < 4; ++tf) {
                ah[tf] = *(const half8*)(ab + aoff[tf]);
                al[tf] = *(const half8*)(ab + 8192 + aoff[tf]);
            }
            #pragma unroll
            for (int jf = 0; jf < 4; ++jf) {
                bh[jf] = *(const half8*)(bb + boff[jf]);
                bl[jf] = *(const half8*)(bb + 16384 + boff[jf]);
            }
            #pragma unroll
            for (int tf = 0; tf < 4; ++tf)
                #pragma unroll
                for (int jf = 0; jf < 4; ++jf) {
                    acc1[tf][jf] = mfma16(ah[tf], bh[jf], acc1[tf][jf]);
                    acc1[tf][jf] = mfma16(ah[tf], bl[jf], acc1[tf][jf]);
                    acc1[tf][jf] = mfma16(al[tf], bh[jf], acc1[tf][jf]);
                }
            if (more) {
                half8 hh, hl;
                split8(xv0, xv1, hh, hl);
                const int g = (akoct*128 + arow) * 16;
                *(half8*)(smem + nxt*SZ_A + g) = hh;
                *(half8*)(smem + nxt*SZ_A + 8192 + g) = hl;
            }
            __syncthreads();
        }
        #pragma unroll
        for (int r = 0; r < 2; ++r) {
            #pragma unroll
            for (int c = 0; c < 2; ++c) {
                const int jf = 2*r + c;
                #pragma unroll
                for (int tf = 0; tf < 4; ++tf)
                    #pragma unroll
                    for (int rr = 0; rr < 4; ++rr) {
                        const float v = acc1[tf][jf][rr];
                        const float gv = 0.5f * v * (1.0f + erff(v * 0.70710678118654752f));
                        const _Float16 gh = (_Float16)gv;
                        const _Float16 gl = (_Float16)(gv - (float)gh);
                        const int o = (tf*16 + lg*4 + rr) * HS + c*16 + l15;
                        myHh[o] = gh; myHl[o] = gl;
                    }
            }
            __syncthreads();
            #pragma unroll
            for (int s = 0; s < 4; ++s) {
                const _Float16* sh = (const _Float16*)(smem + (tg*4 + s) * 9216);
                const _Float16* sl = sh + 2304;
                const int jo = jc*32 + s*8 + r*4 + lg;
                const size_t wg = ((size_t)jo * 64 + jg*16 + l15) * 8;
                half8 b2h = *(const half8*)(W2h + wg);
                half8 b2l = *(const half8*)(W2l + wg);
                #pragma unroll
                for (int tf = 0; tf < 4; ++tf) {
                    const int o = (tf*16 + l15) * HS + lg*8;
                    half8 a2h = *(const half8*)(sh + o);
                    half8 a2l = *(const half8*)(sl + o);
                    lacc[tf] = mfma16(a2h, b2h, lacc[tf]);
                    lacc[tf] = mfma16(a2h, b2l, lacc[tf]);
                    lacc[tf] = mfma16(a2l, b2h, lacc[tf]);
                }
            }
            __syncthreads();
        }
    }
    float* const Lred = (float*)(smem + OFF_LRED);
    #pragma unroll
    for (int tf = 0; tf < 4; ++tf)
        #pragma unroll
        for (int rr = 0; rr < 4; ++rr)
            Lred[(tg*64 + tf*16 + lg*4 + rr) * 68 + jg*16 + l15] = lacc[tf][rr];
    __syncthreads();
    float* const mA   = (float*)(smem + OFF_EPI);
    float* const invA = mA + BM;
    int*   const i1A  = (int*)(invA + BM);
    int*   const i2A  = i1A + BM;
    float* const rp1A = (float*)(i2A + BM);
    float* const rp2A = rp1A + BM;
    if (tid < BM) {
        const float* row = Lred + tid * 68;
        float m = -3.402823466e38f;
        for (int e = 0; e < NE; ++e) m = fmaxf(m, row[e]);
        float s = 0.f, v1 = -3.402823466e38f, v2 = -3.402823466e38f;
        int i1 = 0, i2 = 0;
        for (int e = 0; e < NE; ++e) {
            const float v = row[e];
            s += expf(v - m);
            if (v > v1)      { v2 = v1; i2 = i1; v1 = v; i1 = e; }
            else if (v > v2) { v2 = v; i2 = e; }
        }
        const float inv = 1.f / s;
        const float p1 = fminf(expf(v1 - m) * inv + EPSV, 1.f - EPSV);
        const float p2 = fminf(expf(v2 - m) * inv + EPSV, 1.f - EPSV);
        mA[tid] = m; invA[tid] = inv; i1A[tid] = i1; i2A[tid] = i2;
        const float den = p1 + p2;
        rp1A[tid] = p1 / den; rp2A[tid] = p2 / den;
    }
    __syncthreads();
    for (int idx = tid; idx < BM * NE; idx += NTH) {
        const int r = idx >> 6, e = idx & 63;
        const size_t o = (size_t)(t0 + r) * NE + e;
        const float p = fminf(expf(Lred[r * 68 + e] - mA[r]) * invA[r] + EPSV, 1.f - EPSV);
        const int b1 = (e == i1A[r]), b2 = (e == i2A[r]);
        out_probs[o] = p;
        out_mask[o]  = (b1 | b2) ? 1.f : 0.f;
        out_rp[o]    = b1 ? rp1A[r] : (b2 ? rp2A[r] : 0.f);
    }
    if (tid < BM * 2) {
        const int r = tid >> 1, q = tid & 1;
        out_topi[(size_t)(t0 + r) * 2 + q] = (float)(q ? i2A[r] : i1A[r]);
    }
}

extern "C" void kernel_launch(void* const* d_in, const int* in_sizes, int n_in,
                              void* d_out, int out_size, void* d_ws, size_t ws_size,
                              hipStream_t stream) {
    const float* inp = (const float*)d_in[0];
    const float* cnd = (const float*)d_in[1];
    const float* W1  = (const float*)d_in[2];
    const float* W2  = (const float*)d_in[3];

    float* out = (float*)d_out;
    const size_t NT = (size_t)N_TOK;
    float* out_mask  = out;
    float* out_topi  = out + NT * NE;
    float* out_rp    = out + NT * NE + NT * 2;
    float* out_probs = out + NT * NE + NT * 2 + NT * NE;

    const size_t V16_REQ = (2*XTN + 2*W1N + 2*W2N) * 2;   // ~221 MB
    if (ws_size >= V16_REQ) {
        _Float16* Xh  = (_Float16*)d_ws;
        _Float16* Xl  = Xh + XTN;
        _Float16* W1h = Xl + XTN;
        _Float16* W1l = W1h + W1N;
        _Float16* W2h = W1l + W1N;
        _Float16* W2l = W2h + W2N;
        hipLaunchKernelGGL(presplit_xt,  dim3(XT_G/256), dim3(256), 0, stream, inp, cnd, Xh, Xl);
        hipLaunchKernelGGL(presplit_w1t, dim3((W1T_G + 255)/256), dim3(256), 0, stream, W1, W1h, W1l);
        hipLaunchKernelGGL(presplit_w2t, dim3((W2T_G + 255)/256), dim3(256), 0, stream, W2, W2h, W2l);
        hipLaunchKernelGGL(router_v16, dim3(N_TOK / BM), dim3(NTH), 0, stream,
                           Xh, Xl, W1h, W1l, W2h, W2l,
                           out_mask, out_topi, out_rp, out_probs);
    } else {
        _Float16* W1h = (_Float16*)d_ws;
        _Float16* W1l = W1h + W1N;
        _Float16* W2h = W1l + W1N;
        _Float16* W2l = W2h + W2N;
        hipLaunchKernelGGL(presplit_w1t, dim3((W1T_G + 255)/256), dim3(256), 0, stream, W1, W1h, W1l);
        hipLaunchKernelGGL(presplit_w2t, dim3((W2T_G + 255)/256), dim3(256), 0, stream, W2, W2h, W2l);
        hipLaunchKernelGGL(router_v9fb, dim3(N_TOK / BM), dim3(NTH), 0, stream,
                           inp, cnd, W1h, W1l, W2h, W2l,
                           out_mask, out_topi, out_rp, out_probs);
    }
}

// Round 17
// 1026.043 us; speedup vs baseline: 1.6642x; 1.1179x over previous
//
#include <hip/hip_runtime.h>
#include <cmath>

// RouterCond fused, round 17: r16 zero-VALU staging + 64x128 wave tiles
// (BJ=512, NJC=6) -> LDS bytes per MFMA halves (5.3 -> 2.7 B), MFMA becomes
// the binding pipe. LDS = A dbuf 32KB + B dbuf 128KB = 160 KiB exactly.
#define N_TOK 32768
#define D0    1024
#define DCC   512
#define DIN   1536
#define JD    3072
#define NE    64
#define BM    128
#define BJ    512
#define NJC   (JD/BJ)      // 6
#define NIT   48           // k-steps of 32
#define NTH   512
#define HS    36
#define EPSV  1e-9f

typedef _Float16 half8 __attribute__((ext_vector_type(8)));
typedef float    f32x4 __attribute__((ext_vector_type(4)));

// ---- LDS: A buf [pl2][koct4][row128] granules = 16KB x2.
//      B buf [pl2][koct4][col512] granules = 64KB x2. Total 160 KiB.
#define SZ_A  16384
#define SZ_B  65536
#define OFF_A 0                    // A bufs: 0, 16384
#define OFF_B 32768                // B bufs: 32768, 98304
#define LDS_TOTAL 163840
#define OFF_H    0                 // 8 x 9216 = 73728, aliases A+B0 (fenced)
#define OFF_LRED 73728             // [128][68] f32 = 34816
#define OFF_EPI  (73728 + 34816)

#define W1N   ((size_t)JD*DIN)
#define W2N   ((size_t)NE*JD)
#define XTN   ((size_t)N_TOK*DIN)
#define XT_G  (256*192*128)
#define W1T_G (192*3072)
#define W2T_G (384*64)

__device__ __forceinline__ f32x4 mfma16(half8 a, half8 b, f32x4 c) {
    return __builtin_amdgcn_mfma_f32_16x16x32_f16(a, b, c, 0, 0, 0);
}

__device__ __forceinline__ void split8(const float4 v0, const float4 v1, half8& hh, half8& hl) {
    float f[8] = {v0.x, v0.y, v0.z, v0.w, v1.x, v1.y, v1.z, v1.w};
    #pragma unroll
    for (int i = 0; i < 8; ++i) {
        _Float16 h = (_Float16)f[i];
        hh[i] = h;
        hl[i] = (_Float16)(f[i] - (float)h);
    }
}

__device__ __forceinline__ void gload16(const void* g, void* l) {
    __builtin_amdgcn_global_load_lds(
        (const __attribute__((address_space(1))) unsigned int*)g,
        (__attribute__((address_space(3))) unsigned int*)l, 16, 0, 0);
}

// -------- presplit kernels (r16-proven) --------
__global__ void presplit_w1t(const float* __restrict__ W1,
                             _Float16* __restrict__ hi, _Float16* __restrict__ lo) {
    int g = blockIdx.x * blockDim.x + threadIdx.x;
    if (g >= W1T_G) return;
    const int j  = g % JD;
    const int ko = g / JD;
    const float* src = W1 + (size_t)j * DIN + ko * 8;
    float4 v0 = *(const float4*)src;
    float4 v1 = *(const float4*)(src + 4);
    half8 h, l;
    split8(v0, v1, h, l);
    *(half8*)(hi + (size_t)g * 8) = h;
    *(half8*)(lo + (size_t)g * 8) = l;
}

__global__ void presplit_w2t(const float* __restrict__ W2,
                             _Float16* __restrict__ hi, _Float16* __restrict__ lo) {
    int g = blockIdx.x * blockDim.x + threadIdx.x;
    if (g >= W2T_G) return;
    const int e  = g & 63;
    const int jo = g >> 6;
    const float* src = W2 + (size_t)e * JD + jo * 8;
    float4 v0 = *(const float4*)src;
    float4 v1 = *(const float4*)(src + 4);
    half8 h, l;
    split8(v0, v1, h, l);
    *(half8*)(hi + (size_t)g * 8) = h;
    *(half8*)(lo + (size_t)g * 8) = l;
}

__global__ void presplit_xt(const float* __restrict__ inp, const float* __restrict__ cnd,
                            _Float16* __restrict__ hi, _Float16* __restrict__ lo) {
    int g = blockIdx.x * blockDim.x + threadIdx.x;
    if (g >= XT_G) return;
    const int r    = g & 127;
    const int ko   = (g >> 7) % 192;
    const int tile = g / (192 * 128);
    const int token = tile * 128 + r;
    const float* src = (ko < 128) ? (inp + (size_t)token * D0 + ko * 8)
                                  : (cnd + (size_t)token * DCC + (ko - 128) * 8);
    float4 v0 = *(const float4*)src;
    float4 v1 = *(const float4*)(src + 4);
    half8 h, l;
    split8(v0, v1, h, l);
    *(half8*)(hi + (size_t)g * 8) = h;
    *(half8*)(lo + (size_t)g * 8) = l;
}

// ================= v17 main kernel =================
__global__ __launch_bounds__(NTH, 1)
void router_v17(const _Float16* __restrict__ Xh, const _Float16* __restrict__ Xl,
                const _Float16* __restrict__ W1h, const _Float16* __restrict__ W1l,
                const _Float16* __restrict__ W2h, const _Float16* __restrict__ W2l,
                float* __restrict__ out_mask, float* __restrict__ out_topi,
                float* __restrict__ out_rp, float* __restrict__ out_probs)
{
    __shared__ __align__(16) char smem[LDS_TOTAL];

    const int tid  = threadIdx.x;
    const int lane = tid & 63;
    const int w    = tid >> 6;      // wave 0..7
    const int tg   = w >> 2;        // token half: rows tg*64..+63
    const int jg   = w & 3;         // j quarter (128 cols) / expert group (16)
    const int l15  = lane & 15;
    const int lg   = lane >> 4;     // k-oct 0..3
    const int blk  = blockIdx.x;
    const int t0   = blk * BM;

    // staging roles (A and B): plane = w>>2, koct = w&3
    const int spl = w >> 2;
    const int sko = w & 3;

    // frag byte offsets (hi plane; lo: A +8192, B +32768)
    int aoff[4], boff[8];
    #pragma unroll
    for (int tf = 0; tf < 4; ++tf) aoff[tf] = (lg*128 + tg*64 + tf*16 + l15) * 16;
    #pragma unroll
    for (int jf = 0; jf < 8; ++jf) boff[jf] = lg*8192 + (jg*128 + jf*16 + l15) * 16;

    const f32x4 vzero = {0.f, 0.f, 0.f, 0.f};
    f32x4 lacc[4] = {vzero, vzero, vzero, vzero};   // 64 tok x 16 experts

    const _Float16* const Wbp = spl ? W1l : W1h;
    const _Float16* const Xbp = spl ? Xl  : Xh;
    const size_t xbase = (size_t)blk * 192 * 128;

    _Float16* const myHh = (_Float16*)(smem + OFF_H + w * 9216);
    _Float16* const myHl = myHh + 2304;

    for (int jc = 0; jc < NJC; ++jc) {
        f32x4 acc1[4][8];
        #pragma unroll
        for (int tf = 0; tf < 4; ++tf)
            #pragma unroll
            for (int jf = 0; jf < 8; ++jf) acc1[tf][jf] = vzero;

        // ---- prologue: stage it=0 into buf0 (A: 2 gload16, B: 8 gload16)
        {
            const _Float16* asrc = Xbp + (xbase + (size_t)sko * 128) * 8;
            char* adst = smem + OFF_A + spl * 8192 + sko * 2048;
            gload16(asrc + (size_t)lane * 8, adst);
            gload16(asrc + (size_t)(64 + lane) * 8, adst + 1024);
            const _Float16* bsrc = Wbp + ((size_t)sko * JD + jc * BJ) * 8;
            char* bdst = smem + OFF_B + spl * 32768 + sko * 8192;
            #pragma unroll
            for (int q = 0; q < 8; ++q)
                gload16(bsrc + (size_t)(q * 64 + lane) * 8, bdst + q * 1024);
        }
        __syncthreads();

        for (int it = 0; it < NIT; ++it) {
            const int cur = it & 1, nxt = cur ^ 1;
            const bool more = (it + 1 < NIT);
            if (more) {   // stage it+1 (zero-VALU gload16 path)
                const _Float16* asrc = Xbp + (xbase + (size_t)((it + 1) * 4 + sko) * 128) * 8;
                char* adst = smem + OFF_A + nxt * SZ_A + spl * 8192 + sko * 2048;
                gload16(asrc + (size_t)lane * 8, adst);
                gload16(asrc + (size_t)(64 + lane) * 8, adst + 1024);
                const _Float16* bsrc = Wbp +
                    ((size_t)((it + 1) * 4 + sko) * JD + jc * BJ) * 8;
                char* bdst = smem + OFF_B + nxt * SZ_B + spl * 32768 + sko * 8192;
                #pragma unroll
                for (int q = 0; q < 8; ++q)
                    gload16(bsrc + (size_t)(q * 64 + lane) * 8, bdst + q * 1024);
            }
            const char* ab = smem + OFF_A + cur * SZ_A;
            const char* bb = smem + OFF_B + cur * SZ_B;
            half8 ah[4], al[4];
            #pragma unroll
            for (int tf = 0; tf < 4; ++tf) {
                ah[tf] = *(const half8*)(ab + aoff[tf]);
                al[tf] = *(const half8*)(ab + 8192 + aoff[tf]);
            }
            #pragma unroll
            for (int jf = 0; jf < 8; ++jf) {   // per-jf B loads keep pressure low
                half8 bh = *(const half8*)(bb + boff[jf]);
                half8 bl = *(const half8*)(bb + 32768 + boff[jf]);
                #pragma unroll
                for (int tf = 0; tf < 4; ++tf) {
                    acc1[tf][jf] = mfma16(ah[tf], bh, acc1[tf][jf]);
                    acc1[tf][jf] = mfma16(ah[tf], bl, acc1[tf][jf]);
                    acc1[tf][jf] = mfma16(al[tf], bh, acc1[tf][jf]);
                }
            }
            __syncthreads();   // drains it+1 gloads (issued a full iter ago)
        }

        // ---- GELU + expert-split GEMM2: 4 rounds of 32-j chunks per wave
        #pragma unroll
        for (int r = 0; r < 4; ++r) {
            #pragma unroll
            for (int c = 0; c < 2; ++c) {
                const int jf = 2*r + c;
                #pragma unroll
                for (int tf = 0; tf < 4; ++tf)
                    #pragma unroll
                    for (int rr = 0; rr < 4; ++rr) {
                        const float v = acc1[tf][jf][rr];
                        const float gv = 0.5f * v * (1.0f + erff(v * 0.70710678118654752f));
                        const _Float16 gh = (_Float16)gv;
                        const _Float16 gl = (_Float16)(gv - (float)gh);
                        const int o = (tf*16 + lg*4 + rr) * HS + c*16 + l15;
                        myHh[o] = gh; myHl[o] = gl;
                    }
            }
            __syncthreads();
            #pragma unroll
            for (int s = 0; s < 4; ++s) {
                const _Float16* sh = (const _Float16*)(smem + OFF_H + (tg*4 + s) * 9216);
                const _Float16* sl = sh + 2304;
                const int jo = jc*64 + s*16 + r*4 + lg;
                const size_t wg = ((size_t)jo * 64 + jg*16 + l15) * 8;
                half8 b2h = *(const half8*)(W2h + wg);
                half8 b2l = *(const half8*)(W2l + wg);
                #pragma unroll
                for (int tf = 0; tf < 4; ++tf) {
                    const int o = (tf*16 + l15) * HS + lg*8;
                    half8 a2h = *(const half8*)(sh + o);
                    half8 a2l = *(const half8*)(sl + o);
                    lacc[tf] = mfma16(a2h, b2h, lacc[tf]);
                    lacc[tf] = mfma16(a2h, b2l, lacc[tf]);
                    lacc[tf] = mfma16(a2l, b2h, lacc[tf]);
                }
            }
            __syncthreads();
        }
    }

    // ---- epilogue (r9/r16-proven)
    float* const Lred = (float*)(smem + OFF_LRED);
    #pragma unroll
    for (int tf = 0; tf < 4; ++tf)
        #pragma unroll
        for (int rr = 0; rr < 4; ++rr)
            Lred[(tg*64 + tf*16 + lg*4 + rr) * 68 + jg*16 + l15] = lacc[tf][rr];
    __syncthreads();

    float* const mA   = (float*)(smem + OFF_EPI);
    float* const invA = mA + BM;
    int*   const i1A  = (int*)(invA + BM);
    int*   const i2A  = i1A + BM;
    float* const rp1A = (float*)(i2A + BM);
    float* const rp2A = rp1A + BM;

    if (tid < BM) {
        const float* row = Lred + tid * 68;
        float m = -3.402823466e38f;
        for (int e = 0; e < NE; ++e) m = fmaxf(m, row[e]);
        float s = 0.f, v1 = -3.402823466e38f, v2 = -3.402823466e38f;
        int i1 = 0, i2 = 0;
        for (int e = 0; e < NE; ++e) {
            const float v = row[e];
            s += expf(v - m);
            if (v > v1)      { v2 = v1; i2 = i1; v1 = v; i1 = e; }
            else if (v > v2) { v2 = v; i2 = e; }
        }
        const float inv = 1.f / s;
        const float p1 = fminf(expf(v1 - m) * inv + EPSV, 1.f - EPSV);
        const float p2 = fminf(expf(v2 - m) * inv + EPSV, 1.f - EPSV);
        mA[tid] = m; invA[tid] = inv; i1A[tid] = i1; i2A[tid] = i2;
        const float den = p1 + p2;
        rp1A[tid] = p1 / den; rp2A[tid] = p2 / den;
    }
    __syncthreads();

    for (int idx = tid; idx < BM * NE; idx += NTH) {
        const int r = idx >> 6, e = idx & 63;
        const size_t o = (size_t)(t0 + r) * NE + e;
        const float p = fminf(expf(Lred[r * 68 + e] - mA[r]) * invA[r] + EPSV, 1.f - EPSV);
        const int b1 = (e == i1A[r]), b2 = (e == i2A[r]);
        out_probs[o] = p;
        out_mask[o]  = (b1 | b2) ? 1.f : 0.f;
        out_rp[o]    = b1 ? rp1A[r] : (b2 ? rp2A[r] : 0.f);
    }
    if (tid < BM * 2) {
        const int r = tid >> 1, q = tid & 1;
        out_topi[(size_t)(t0 + r) * 2 + q] = (float)(q ? i2A[r] : i1A[r]);
    }
}

// ================= r16 fallback path (ws-small): r9fb =================
#define FB_SZ_A  16384
#define FB_SZ_B  32768
#define FB_OFF_B 32768
#define FB_LDS   98304

__global__ __launch_bounds__(NTH, 1)
void router_v9fb(const float* __restrict__ inp, const float* __restrict__ cnd,
                 const _Float16* __restrict__ W1h, const _Float16* __restrict__ W1l,
                 const _Float16* __restrict__ W2h, const _Float16* __restrict__ W2l,
                 float* __restrict__ out_mask, float* __restrict__ out_topi,
                 float* __restrict__ out_rp, float* __restrict__ out_probs)
{
    __shared__ __align__(16) char smem[FB_LDS];
    const int tid  = threadIdx.x;
    const int lane = tid & 63;
    const int w    = tid >> 6;
    const int tg   = w >> 2;
    const int jg   = w & 3;
    const int l15  = lane & 15;
    const int lg   = lane >> 4;
    const int t0   = blockIdx.x * BM;
    const int akoct = w >> 1;
    const int arow  = (w & 1) * 64 + lane;
    const int bplane = w >> 2;
    const int bkoct  = w & 3;

    int aoff[4], boff[4];
    #pragma unroll
    for (int tf = 0; tf < 4; ++tf) aoff[tf] = (lg*128 + tg*64 + tf*16 + l15) * 16;
    #pragma unroll
    for (int jf = 0; jf < 4; ++jf) boff[jf] = (lg*256 + jg*64 + jf*16 + l15) * 16;

    const f32x4 vzero = {0.f, 0.f, 0.f, 0.f};
    f32x4 lacc[4] = {vzero, vzero, vzero, vzero};
    const float* const xrowA = inp + (size_t)(t0 + arow) * D0;
    const float* const xrowC = cnd + (size_t)(t0 + arow) * DCC;
    const _Float16* const Wbp = bplane ? W1l : W1h;
    _Float16* const myHh = (_Float16*)(smem + w * 9216);
    _Float16* const myHl = myHh + 2304;

    for (int jc = 0; jc < JD/256; ++jc) {
        f32x4 acc1[4][4];
        #pragma unroll
        for (int tf = 0; tf < 4; ++tf)
            #pragma unroll
            for (int jf = 0; jf < 4; ++jf) acc1[tf][jf] = vzero;
        {
            #pragma unroll
            for (int q = 0; q < 4; ++q) {
                const _Float16* src = Wbp + ((size_t)bkoct * JD + jc*256 + q*64 + lane) * 8;
                gload16(src, smem + FB_OFF_B + bplane*16384 + bkoct*4096 + q*1024);
            }
            const float* sx = xrowA + akoct * 8;
            float4 v0 = *(const float4*)sx;
            float4 v1 = *(const float4*)(sx + 4);
            half8 hh, hl;
            split8(v0, v1, hh, hl);
            const int g = (akoct*128 + arow) * 16;
            *(half8*)(smem + g) = hh;
            *(half8*)(smem + 8192 + g) = hl;
        }
        __syncthreads();
        for (int it = 0; it < NIT; ++it) {
            const int cur = it & 1, nxt = cur ^ 1;
            const bool more = (it + 1 < NIT);
            float4 xv0, xv1;
            if (more) {
                const int ko = (it + 1) * 4 + bkoct;
                #pragma unroll
                for (int q = 0; q < 4; ++q) {
                    const _Float16* src = Wbp + ((size_t)ko * JD + jc*256 + q*64 + lane) * 8;
                    gload16(src, smem + FB_OFF_B + nxt*FB_SZ_B + bplane*16384 + bkoct*4096 + q*1024);
                }
                const int k = (it + 1) * 32 + akoct * 8;
                const float* sx = (k < D0) ? (xrowA + k) : (xrowC + k - D0);
                xv0 = *(const float4*)sx;
                xv1 = *(const float4*)(sx + 4);
            }
            const char* ab = smem + cur*FB_SZ_A;
            const char* bb = smem + FB_OFF_B + cur*FB_SZ_B;
            half8 ah[4], al[4], bh[4], bl[4];
            #pragma unroll
            for (int tf = 0; tf < 4; ++tf) {
                ah[tf] = *(const half8*)(ab + aoff[tf]);
                al[tf] = *(const half8*)(ab + 8192 + aoff[tf]);
            }
            #pragma unroll
            for (int jf = 0; jf < 4; ++jf) {
                bh[jf] = *(const half8*)(bb + boff[jf]);
                bl[jf] = *(const half8*)(bb + 16384 + boff[jf]);
            }
            #pragma unroll
            for (int tf = 0; tf < 4; ++tf)
                #pragma unroll
                for (int jf = 0; jf < 4; ++jf) {
                    acc1[tf][jf] = mfma16(ah[tf], bh[jf], acc1[tf][jf]);
                    acc1[tf][jf] = mfma16(ah[tf], bl[jf], acc1[tf][jf]);
                    acc1[tf][jf] = mfma16(al[tf], bh[jf], acc1[tf][jf]);
                }
            if (more) {
                half8 hh, hl;
                split8(xv0, xv1, hh, hl);
                const int g = (akoct*128 + arow) * 16;
                *(half8*)(smem + nxt*FB_SZ_A + g) = hh;
                *(half8*)(smem + nxt*FB_SZ_A + 8192 + g) = hl;
            }
            __syncthreads();
        }
        #pragma unroll
        for (int r = 0; r < 2; ++r) {
            #pragma unroll
            for (int c = 0; c < 2; ++c) {
                const int jf = 2*r + c;
                #pragma unroll
                for (int tf = 0; tf < 4; ++tf)
                    #pragma unroll
                    for (int rr = 0; rr < 4; ++rr) {
                        const float v = acc1[tf][jf][rr];
                        const float gv = 0.5f * v * (1.0f + erff(v * 0.70710678118654752f));
                        const _Float16 gh = (_Float16)gv;
                        const _Float16 gl = (_Float16)(gv - (float)gh);
                        const int o = (tf*16 + lg*4 + rr) * HS + c*16 + l15;
                        myHh[o] = gh; myHl[o] = gl;
                    }
            }
            __syncthreads();
            #pragma unroll
            for (int s = 0; s < 4; ++s) {
                const _Float16* sh = (const _Float16*)(smem + (tg*4 + s) * 9216);
                const _Float16* sl = sh + 2304;
                const int jo = jc*32 + s*8 + r*4 + lg;
                const size_t wg = ((size_t)jo * 64 + jg*16 + l15) * 8;
                half8 b2h = *(const half8*)(W2h + wg);
                half8 b2l = *(const half8*)(W2l + wg);
                #pragma unroll
                for (int tf = 0; tf < 4; ++tf) {
                    const int o = (tf*16 + l15) * HS + lg*8;
                    half8 a2h = *(const half8*)(sh + o);
                    half8 a2l = *(const half8*)(sl + o);
                    lacc[tf] = mfma16(a2h, b2h, lacc[tf]);
                    lacc[tf] = mfma16(a2h, b2l, lacc[tf]);
                    lacc[tf] = mfma16(a2l, b2h, lacc[tf]);
                }
            }
            __syncthreads();
        }
    }
    float* const Lred = (float*)smem;
    #pragma unroll
    for (int tf = 0; tf < 4; ++tf)
        #pragma unroll
        for (int rr = 0; rr < 4; ++rr)
            Lred[(tg*64 + tf*16 + lg*4 + rr) * 68 + jg*16 + l15] = lacc[tf][rr];
    __syncthreads();
    float* const mA   = (float*)(smem + 36864);
    float* const invA = mA + BM;
    int*   const i1A  = (int*)(invA + BM);
    int*   const i2A  = i1A + BM;
    float* const rp1A = (float*)(i2A + BM);
    float* const rp2A = rp1A + BM;
    if (tid < BM) {
        const float* row = Lred + tid * 68;
        float m = -3.402823466e38f;
        for (int e = 0; e < NE; ++e) m = fmaxf(m, row[e]);
        float s = 0.f, v1 = -3.402823466e38f, v2 = -3.402823466e38f;
        int i1 = 0, i2 = 0;
        for (int e = 0; e < NE; ++e) {
            const float v = row[e];
            s += expf(v - m);
            if (v > v1)      { v2 = v1; i2 = i1; v1 = v; i1 = e; }
            else if (v > v2) { v2 = v; i2 = e; }
        }
        const float inv = 1.f / s;
        const float p1 = fminf(expf(v1 - m) * inv + EPSV, 1.f - EPSV);
        const float p2 = fminf(expf(v2 - m) * inv + EPSV, 1.f - EPSV);
        mA[tid] = m; invA[tid] = inv; i1A[tid] = i1; i2A[tid] = i2;
        const float den = p1 + p2;
        rp1A[tid] = p1 / den; rp2A[tid] = p2 / den;
    }
    __syncthreads();
    for (int idx = tid; idx < BM * NE; idx += NTH) {
        const int r = idx >> 6, e = idx & 63;
        const size_t o = (size_t)(t0 + r) * NE + e;
        const float p = fminf(expf(Lred[r * 68 + e] - mA[r]) * invA[r] + EPSV, 1.f - EPSV);
        const int b1 = (e == i1A[r]), b2 = (e == i2A[r]);
        out_probs[o] = p;
        out_mask[o]  = (b1 | b2) ? 1.f : 0.f;
        out_rp[o]    = b1 ? rp1A[r] : (b2 ? rp2A[r] : 0.f);
    }
    if (tid < BM * 2) {
        const int r = tid >> 1, q = tid & 1;
        out_topi[(size_t)(t0 + r) * 2 + q] = (float)(q ? i2A[r] : i1A[r]);
    }
}

extern "C" void kernel_launch(void* const* d_in, const int* in_sizes, int n_in,
                              void* d_out, int out_size, void* d_ws, size_t ws_size,
                              hipStream_t stream) {
    const float* inp = (const float*)d_in[0];
    const float* cnd = (const float*)d_in[1];
    const float* W1  = (const float*)d_in[2];
    const float* W2  = (const float*)d_in[3];

    float* out = (float*)d_out;
    const size_t NT = (size_t)N_TOK;
    float* out_mask  = out;
    float* out_topi  = out + NT * NE;
    float* out_rp    = out + NT * NE + NT * 2;
    float* out_probs = out + NT * NE + NT * 2 + NT * NE;

    const size_t V17_REQ = (2*XTN + 2*W1N + 2*W2N) * 2;   // ~221 MB
    if (ws_size >= V17_REQ) {
        _Float16* Xh  = (_Float16*)d_ws;
        _Float16* Xl  = Xh + XTN;
        _Float16* W1h = Xl + XTN;
        _Float16* W1l = W1h + W1N;
        _Float16* W2h = W1l + W1N;
        _Float16* W2l = W2h + W2N;
        hipLaunchKernelGGL(presplit_xt,  dim3(XT_G/256), dim3(256), 0, stream, inp, cnd, Xh, Xl);
        hipLaunchKernelGGL(presplit_w1t, dim3((W1T_G + 255)/256), dim3(256), 0, stream, W1, W1h, W1l);
        hipLaunchKernelGGL(presplit_w2t, dim3((W2T_G + 255)/256), dim3(256), 0, stream, W2, W2h, W2l);
        hipLaunchKernelGGL(router_v17, dim3(N_TOK / BM), dim3(NTH), 0, stream,
                           Xh, Xl, W1h, W1l, W2h, W2l,
                           out_mask, out_topi, out_rp, out_probs);
    } else {
        _Float16* W1h = (_Float16*)d_ws;
        _Float16* W1l = W1h + W1N;
        _Float16* W2h = W1l + W1N;
        _Float16* W2l = W2h + W2N;
        hipLaunchKernelGGL(presplit_w1t, dim3((W1T_G + 255)/256), dim3(256), 0, stream, W1, W1h, W1l);
        hipLaunchKernelGGL(presplit_w2t, dim3((W2T_G + 255)/256), dim3(256), 0, stream, W2, W2h, W2l);
        hipLaunchKernelGGL(router_v9fb, dim3(N_TOK / BM), dim3(NTH), 0, stream,
                           inp, cnd, W1h, W1l, W2h, W2l,
                           out_mask, out_topi, out_rp, out_probs);
    }
}